// Round 1
// baseline (1012.454 us; speedup 1.0000x reference)
//
#include <hip/hip_runtime.h>
#include <hip/hip_bf16.h>
#include <type_traits>

typedef __attribute__((ext_vector_type(8))) __bf16 bf16x8;
typedef __attribute__((ext_vector_type(4))) float f32x4;
typedef unsigned short u16;

__device__ __forceinline__ u16 f2b(float x) {
  union { __hip_bfloat16 b; u16 u; } cv;
  cv.b = __float2bfloat16(x);
  return cv.u;
}

// ---------------------------------------------------------------------------
// Templated B^T GEMM: C[m,n] = sum_k A[m,k] * Bt[n,k]  (+ epilogue)
// TA/TB: float (converted to bf16 while staging to LDS) or u16 (raw bf16)
// TC: u16 (bf16 out) or float
// EPI: 0 none, 1 += bias[n], 2 mask? -1e9 : v*scale
// Tile: BM=BN=128, BK=32, 256 threads = 4 waves, each wave 64x64 via
// 4x4 grid of mfma_f32_16x16x32_bf16.
// ---------------------------------------------------------------------------
constexpr int BM = 128, BN = 128, BK = 32, SK = BK + 8;  // SK pad kills stride-64B conflicts

enum { EPI_NONE = 0, EPI_BIAS = 1, EPI_MASK = 2 };

template <typename TA, typename TB, typename TC, int EPI>
__global__ __launch_bounds__(256)
void gemm_bt(const TA* __restrict__ A, const TB* __restrict__ Bt,
             TC* __restrict__ C, const float* __restrict__ bias,
             const int* __restrict__ mask, float scale,
             int M, int N, int K,
             long long sA, long long sB, long long sC, long long sM) {
  __shared__ u16 As[BM * SK];
  __shared__ u16 Bs[BN * SK];

  const int bz = blockIdx.z;
  A  += (size_t)bz * sA;
  Bt += (size_t)bz * sB;
  C  += (size_t)bz * sC;
  const long long maskBase = (long long)bz * sM;

  const int m0 = blockIdx.y * BM;
  const int n0 = blockIdx.x * BN;
  const int t = threadIdx.x;
  const int wave = t >> 6, lane = t & 63;
  const int wm = (wave >> 1) * 64, wn = (wave & 1) * 64;
  const int fr = lane & 15, quad = lane >> 4;

  f32x4 acc[4][4] = {};

  for (int k0 = 0; k0 < K; k0 += BK) {
    // ---- stage A and Bt tiles (128x32) into LDS as bf16 ----
#pragma unroll
    for (int p = 0; p < 4; ++p) {
      int v = p * 256 + t;
      int r = v >> 3, cg = (v & 7) * 4;  // 8 groups of 4 elems per row
      if constexpr (std::is_same_v<TA, float>) {
        float4 d = *(const float4*)&A[(size_t)(m0 + r) * K + k0 + cg];
        ushort4 h;
        h.x = f2b(d.x); h.y = f2b(d.y); h.z = f2b(d.z); h.w = f2b(d.w);
        *(ushort4*)&As[r * SK + cg] = h;
      } else {
        *(ushort4*)&As[r * SK + cg] =
            *(const ushort4*)&A[(size_t)(m0 + r) * K + k0 + cg];
      }
      if constexpr (std::is_same_v<TB, float>) {
        float4 d = *(const float4*)&Bt[(size_t)(n0 + r) * K + k0 + cg];
        ushort4 h;
        h.x = f2b(d.x); h.y = f2b(d.y); h.z = f2b(d.z); h.w = f2b(d.w);
        *(ushort4*)&Bs[r * SK + cg] = h;
      } else {
        *(ushort4*)&Bs[r * SK + cg] =
            *(const ushort4*)&Bt[(size_t)(n0 + r) * K + k0 + cg];
      }
    }
    __syncthreads();

    // ---- fragments + MFMA ----
    bf16x8 af[4], bfr[4];
#pragma unroll
    for (int i = 0; i < 4; ++i)
      af[i] = *(const bf16x8*)&As[(wm + i * 16 + fr) * SK + quad * 8];
#pragma unroll
    for (int j = 0; j < 4; ++j)
      bfr[j] = *(const bf16x8*)&Bs[(wn + j * 16 + fr) * SK + quad * 8];
#pragma unroll
    for (int i = 0; i < 4; ++i)
#pragma unroll
      for (int j = 0; j < 4; ++j)
        acc[i][j] = __builtin_amdgcn_mfma_f32_16x16x32_bf16(af[i], bfr[j],
                                                            acc[i][j], 0, 0, 0);
    __syncthreads();
  }

  // ---- epilogue: C/D layout col=lane&15, row=quad*4+reg ----
#pragma unroll
  for (int i = 0; i < 4; ++i)
#pragma unroll
    for (int j = 0; j < 4; ++j)
#pragma unroll
      for (int r = 0; r < 4; ++r) {
        int m = m0 + wm + i * 16 + quad * 4 + r;
        int n = n0 + wn + j * 16 + fr;
        float v = acc[i][j][r];
        if constexpr (EPI == EPI_BIAS) v += bias[n];
        if constexpr (EPI == EPI_MASK)
          v = mask[maskBase + (size_t)m * N + n] ? -1e9f : v * scale;
        if constexpr (std::is_same_v<TC, u16>)
          C[(size_t)m * N + n] = f2b(v);
        else
          C[(size_t)m * N + n] = v;
      }
}

// ---------------------------------------------------------------------------
// V [8][2048][1024] bf16 -> Vt [8][1024][2048] bf16, 64x64 LDS tiles
// ---------------------------------------------------------------------------
__global__ __launch_bounds__(256)
void transpose_v(const u16* __restrict__ V, u16* __restrict__ Vt) {
  __shared__ u16 tile[64][68];  // stride 136B -> 2-way conflict only (free)
  const int b = blockIdx.z;
  const int f0 = blockIdx.x * 64;  // 16 blocks over 1024
  const int j0 = blockIdx.y * 64;  // 32 blocks over 2048
  const u16* Vb = V + (size_t)b * 2048 * 1024;
  u16* Vtb = Vt + (size_t)b * 1024 * 2048;
  const int t = threadIdx.x;
#pragma unroll
  for (int p = 0; p < 4; ++p) {
    int v = p * 256 + t;
    int r = v >> 4, cg = (v & 15) * 4;
    *(ushort4*)&tile[r][cg] =
        *(const ushort4*)&Vb[(size_t)(j0 + r) * 1024 + f0 + cg];
  }
  __syncthreads();
#pragma unroll
  for (int p = 0; p < 4; ++p) {
    int v = p * 256 + t;
    int r = v >> 4, cg = (v & 15) * 4;  // r: f-local, cg: j-local
    ushort4 o;
    o.x = tile[cg + 0][r];
    o.y = tile[cg + 1][r];
    o.z = tile[cg + 2][r];
    o.w = tile[cg + 3][r];
    *(ushort4*)&Vtb[(size_t)(f0 + r) * 2048 + j0 + cg] = o;
  }
}

// ---------------------------------------------------------------------------
// In-place row softmax over att [16384][2048] fp32. One 256-thread block/row.
// ---------------------------------------------------------------------------
__device__ __forceinline__ float blockReduceMax(float v, float* red) {
#pragma unroll
  for (int o = 32; o > 0; o >>= 1) v = fmaxf(v, __shfl_down(v, o));
  int t = threadIdx.x;
  if ((t & 63) == 0) red[t >> 6] = v;
  __syncthreads();
  float r = fmaxf(fmaxf(red[0], red[1]), fmaxf(red[2], red[3]));
  __syncthreads();
  return r;
}

__device__ __forceinline__ float blockReduceSum(float v, float* red) {
#pragma unroll
  for (int o = 32; o > 0; o >>= 1) v += __shfl_down(v, o);
  int t = threadIdx.x;
  if ((t & 63) == 0) red[t >> 6] = v;
  __syncthreads();
  float r = red[0] + red[1] + red[2] + red[3];
  __syncthreads();
  return r;
}

__global__ __launch_bounds__(256)
void softmax_rows(float* __restrict__ att) {
  __shared__ float red[4];
  float* p = att + (size_t)blockIdx.x * 2048;
  const int t = threadIdx.x;
  float4 v0 = ((const float4*)p)[t];
  float4 v1 = ((const float4*)p)[t + 256];
  float mx = fmaxf(fmaxf(fmaxf(v0.x, v0.y), fmaxf(v0.z, v0.w)),
                   fmaxf(fmaxf(v1.x, v1.y), fmaxf(v1.z, v1.w)));
  mx = blockReduceMax(mx, red);
  float4 e0, e1;
  e0.x = __expf(v0.x - mx); e0.y = __expf(v0.y - mx);
  e0.z = __expf(v0.z - mx); e0.w = __expf(v0.w - mx);
  e1.x = __expf(v1.x - mx); e1.y = __expf(v1.y - mx);
  e1.z = __expf(v1.z - mx); e1.w = __expf(v1.w - mx);
  float s = (e0.x + e0.y + e0.z + e0.w) + (e1.x + e1.y + e1.z + e1.w);
  s = blockReduceSum(s, red);
  float inv = 1.0f / s;
  e0.x *= inv; e0.y *= inv; e0.z *= inv; e0.w *= inv;
  e1.x *= inv; e1.y *= inv; e1.z *= inv; e1.w *= inv;
  ((float4*)p)[t] = e0;
  ((float4*)p)[t + 256] = e1;
}

// ---------------------------------------------------------------------------
extern "C" void kernel_launch(void* const* d_in, const int* in_sizes, int n_in,
                              void* d_out, int out_size, void* d_ws,
                              size_t ws_size, hipStream_t stream) {
  const float* x   = (const float*)d_in[0];  // [8,2048,1024]
  const float* ctx = (const float*)d_in[1];  // [8,2048,1024]
  const int*   msk = (const int*)d_in[2];    // [8,2048,2048] bool->int
  const float* Wq  = (const float*)d_in[3];  // [1024,1024] (F,E) == B^T
  const float* bq  = (const float*)d_in[4];
  const float* Wk  = (const float*)d_in[5];
  const float* bk  = (const float*)d_in[6];
  const float* Wv  = (const float*)d_in[7];
  const float* bv  = (const float*)d_in[8];

  float* out = (float*)d_out;            // 8*2048*1024 = 16777216
  float* att = out + 16777216;           // 8*2048*2048 = 33554432

  u16* Q  = (u16*)d_ws;                  // 16777216 bf16
  u16* Kb = Q + 16777216;
  u16* V  = Kb + 16777216;
  u16* Vt = V + 16777216;                // total 134 MB of ws

  dim3 blk(256);
  const long long SQ = 2048LL * 1024, SS = 2048LL * 2048, SV = 1024LL * 2048;

  // Q/K/V projections: M=16384, N=1024, K=1024
  gemm_bt<float, float, u16, EPI_BIAS><<<dim3(8, 128, 1), blk, 0, stream>>>(
      x, Wq, Q, bq, nullptr, 0.f, 16384, 1024, 1024, 0, 0, 0, 0);
  gemm_bt<float, float, u16, EPI_BIAS><<<dim3(8, 128, 1), blk, 0, stream>>>(
      ctx, Wk, Kb, bk, nullptr, 0.f, 16384, 1024, 1024, 0, 0, 0, 0);
  gemm_bt<float, float, u16, EPI_BIAS><<<dim3(8, 128, 1), blk, 0, stream>>>(
      ctx, Wv, V, bv, nullptr, 0.f, 16384, 1024, 1024, 0, 0, 0, 0);

  transpose_v<<<dim3(16, 32, 8), blk, 0, stream>>>(V, Vt);

  // logits = Q K^T * scale, masked -> att region (fp32)
  gemm_bt<u16, u16, float, EPI_MASK><<<dim3(16, 16, 8), blk, 0, stream>>>(
      Q, Kb, att, nullptr, msk, 0.03125f, 2048, 2048, 1024, SQ, SQ, SS, SS);

  softmax_rows<<<dim3(16384), blk, 0, stream>>>(att);

  // out = att @ V : A=att fp32 (convert on stage), Bt=Vt bf16
  gemm_bt<float, u16, float, EPI_NONE><<<dim3(8, 16, 8), blk, 0, stream>>>(
      att, Vt, out, nullptr, nullptr, 0.f, 2048, 1024, 2048, SS, SV, SQ, 0);
}

// Round 2
// 906.232 us; speedup vs baseline: 1.1172x; 1.1172x over previous
//
#include <hip/hip_runtime.h>
#include <hip/hip_bf16.h>
#include <type_traits>

typedef __attribute__((ext_vector_type(8))) __bf16 bf16x8;
typedef __attribute__((ext_vector_type(4))) float f32x4;
typedef unsigned short u16;

__device__ __forceinline__ u16 f2b(float x) {
  union { __hip_bfloat16 b; u16 u; } cv;
  cv.b = __float2bfloat16(x);
  return cv.u;
}

// async global->LDS, 16 B per lane. LDS dst = wave-uniform base + lane*16.
__device__ __forceinline__ void ld16(const u16* g, u16* l) {
  __builtin_amdgcn_global_load_lds(
      (const __attribute__((address_space(1))) unsigned int*)g,
      (__attribute__((address_space(3))) unsigned int*)l, 16, 0, 0);
}

constexpr int BM = 128, BN = 128, BK = 32;  // LDS tiles unpadded (async layout)

enum { EPI_NONE = 0, EPI_BIAS = 1, EPI_BIAS_T = 2, EPI_MASK = 3 };

// C[m,n] = sum_k A[m,k] * Bt[n,k] (+ epilogue). A always bf16 (async staged).
// B_F32: B is fp32 (weights), converted to bf16 while staging; else bf16 async.
// EPI_BIAS_T: C = Vt base [8][1024][2048] bf16, writes transposed (seq=2048).
template <bool B_F32, typename TC, int EPI>
__global__ __launch_bounds__(256) void gemm_bt(
    const u16* __restrict__ A, const void* __restrict__ Bv, TC* __restrict__ C,
    const float* __restrict__ bias, const int* __restrict__ mask, float scale,
    int M, int N, int K, long long sA, long long sB, long long sC,
    long long sM) {
  __shared__ u16 As[BM * BK];
  __shared__ u16 Bs[BN * BK];

  const int bz = blockIdx.z;
  A += (size_t)bz * sA;
  C += (size_t)bz * sC;
  const long long maskBase = (long long)bz * sM;

  const int m0 = blockIdx.y * BM, n0 = blockIdx.x * BN;
  const int t = threadIdx.x, wave = t >> 6, lane = t & 63;
  const int wm = (wave >> 1) * 64, wn = (wave & 1) * 64;
  const int fr = lane & 15, quad = lane >> 4;
  const int lrow = lane >> 2, lcol = (lane & 3) * 8;  // 16 rows x 4 chunks/instr

  const u16* ga = A + (size_t)(m0 + wave * 32 + lrow) * K + lcol;
  u16* ldsA0 = &As[(wave * 32) * BK];
  u16* ldsA1 = &As[(wave * 32 + 16) * BK];

  const u16* gb = nullptr;
  const float* Bw = nullptr;
  if constexpr (B_F32) {
    Bw = (const float*)Bv;
  } else {
    gb = (const u16*)Bv + (size_t)bz * sB +
         (size_t)(n0 + wave * 32 + lrow) * K + lcol;
  }
  u16* ldsB0 = &Bs[(wave * 32) * BK];
  u16* ldsB1 = &Bs[(wave * 32 + 16) * BK];

  f32x4 acc[4][4] = {};

  for (int k0 = 0; k0 < K; k0 += BK) {
    ld16(ga, ldsA0);
    ld16(ga + (size_t)16 * K, ldsA1);
    if constexpr (B_F32) {
#pragma unroll
      for (int p = 0; p < 4; ++p) {
        int v = p * 256 + t;
        int r = v >> 3, cg = (v & 7) * 4;
        float4 d = *(const float4*)&Bw[(size_t)(n0 + r) * K + k0 + cg];
        ushort4 h;
        h.x = f2b(d.x); h.y = f2b(d.y); h.z = f2b(d.z); h.w = f2b(d.w);
        *(ushort4*)&Bs[r * BK + cg] = h;
      }
    } else {
      ld16(gb, ldsB0);
      ld16(gb + (size_t)16 * K, ldsB1);
      gb += BK;
    }
    ga += BK;
    __builtin_amdgcn_s_waitcnt(0x0f70);  // vmcnt(0): async LDS writes done
    __syncthreads();

    bf16x8 af[4], bfr[4];
#pragma unroll
    for (int i = 0; i < 4; ++i)
      af[i] = *(const bf16x8*)&As[(wm + i * 16 + fr) * BK + quad * 8];
#pragma unroll
    for (int j = 0; j < 4; ++j)
      bfr[j] = *(const bf16x8*)&Bs[(wn + j * 16 + fr) * BK + quad * 8];
#pragma unroll
    for (int i = 0; i < 4; ++i)
#pragma unroll
      for (int j = 0; j < 4; ++j)
        acc[i][j] = __builtin_amdgcn_mfma_f32_16x16x32_bf16(af[i], bfr[j],
                                                            acc[i][j], 0, 0, 0);
    __syncthreads();
  }

  // C/D layout: col = lane&15 (fr), row = quad*4 + reg
#pragma unroll
  for (int i = 0; i < 4; ++i)
#pragma unroll
    for (int j = 0; j < 4; ++j) {
      const int mb = m0 + wm + i * 16 + quad * 4;
      const int n = n0 + wn + j * 16 + fr;
      if constexpr (EPI == EPI_BIAS_T) {
        const float bb = bias[n];
        const int b = mb >> 11, ml = mb & 2047;  // seq = 2048 per batch
        ushort4 o;
        o.x = f2b(acc[i][j][0] + bb);
        o.y = f2b(acc[i][j][1] + bb);
        o.z = f2b(acc[i][j][2] + bb);
        o.w = f2b(acc[i][j][3] + bb);
        *(ushort4*)&((u16*)C)[(size_t)b * 2097152 + (size_t)n * 2048 + ml] = o;
      } else {
#pragma unroll
        for (int r = 0; r < 4; ++r) {
          const int m = mb + r;
          float v = acc[i][j][r];
          if constexpr (EPI == EPI_BIAS) v += bias[n];
          if constexpr (EPI == EPI_MASK)
            v = mask[maskBase + (size_t)m * N + n] ? -1e9f : v * scale;
          if constexpr (std::is_same_v<TC, u16>)
            C[(size_t)m * N + n] = f2b(v);
          else
            C[(size_t)m * N + n] = v;
        }
      }
    }
}

// ---------------------------------------------------------------------------
// fp32 -> bf16 cast: y selects (a->oa) or (b->ob), 4 elems/thread
// ---------------------------------------------------------------------------
__global__ __launch_bounds__(256) void cast2(const float* __restrict__ a,
                                             const float* __restrict__ b,
                                             u16* __restrict__ oa,
                                             u16* __restrict__ ob) {
  const size_t i = ((size_t)blockIdx.x * 256 + threadIdx.x) * 4;
  const float* s = blockIdx.y ? b : a;
  u16* d = blockIdx.y ? ob : oa;
  float4 v = *(const float4*)&s[i];
  ushort4 h;
  h.x = f2b(v.x); h.y = f2b(v.y); h.z = f2b(v.z); h.w = f2b(v.w);
  *(ushort4*)&d[i] = h;
}

// ---------------------------------------------------------------------------
// In-place row softmax over att [16384][2048] fp32 + bf16 copy for AV GEMM.
// ---------------------------------------------------------------------------
__device__ __forceinline__ float blockReduceMax(float v, float* red) {
#pragma unroll
  for (int o = 32; o > 0; o >>= 1) v = fmaxf(v, __shfl_down(v, o));
  int t = threadIdx.x;
  if ((t & 63) == 0) red[t >> 6] = v;
  __syncthreads();
  float r = fmaxf(fmaxf(red[0], red[1]), fmaxf(red[2], red[3]));
  __syncthreads();
  return r;
}

__device__ __forceinline__ float blockReduceSum(float v, float* red) {
#pragma unroll
  for (int o = 32; o > 0; o >>= 1) v += __shfl_down(v, o);
  int t = threadIdx.x;
  if ((t & 63) == 0) red[t >> 6] = v;
  __syncthreads();
  float r = red[0] + red[1] + red[2] + red[3];
  __syncthreads();
  return r;
}

__global__ __launch_bounds__(256) void softmax_rows(float* __restrict__ att,
                                                    u16* __restrict__ attb) {
  __shared__ float red[4];
  float* p = att + (size_t)blockIdx.x * 2048;
  u16* pb = attb + (size_t)blockIdx.x * 2048;
  const int t = threadIdx.x;
  float4 v0 = ((const float4*)p)[t];
  float4 v1 = ((const float4*)p)[t + 256];
  float mx = fmaxf(fmaxf(fmaxf(v0.x, v0.y), fmaxf(v0.z, v0.w)),
                   fmaxf(fmaxf(v1.x, v1.y), fmaxf(v1.z, v1.w)));
  mx = blockReduceMax(mx, red);
  float4 e0, e1;
  e0.x = __expf(v0.x - mx); e0.y = __expf(v0.y - mx);
  e0.z = __expf(v0.z - mx); e0.w = __expf(v0.w - mx);
  e1.x = __expf(v1.x - mx); e1.y = __expf(v1.y - mx);
  e1.z = __expf(v1.z - mx); e1.w = __expf(v1.w - mx);
  float s = (e0.x + e0.y + e0.z + e0.w) + (e1.x + e1.y + e1.z + e1.w);
  s = blockReduceSum(s, red);
  float inv = 1.0f / s;
  e0.x *= inv; e0.y *= inv; e0.z *= inv; e0.w *= inv;
  e1.x *= inv; e1.y *= inv; e1.z *= inv; e1.w *= inv;
  ((float4*)p)[t] = e0;
  ((float4*)p)[t + 256] = e1;
  ushort4 h0, h1;
  h0.x = f2b(e0.x); h0.y = f2b(e0.y); h0.z = f2b(e0.z); h0.w = f2b(e0.w);
  h1.x = f2b(e1.x); h1.y = f2b(e1.y); h1.z = f2b(e1.z); h1.w = f2b(e1.w);
  *(ushort4*)&pb[(size_t)t * 4] = h0;
  *(ushort4*)&pb[(size_t)(t + 256) * 4] = h1;
}

// ---------------------------------------------------------------------------
extern "C" void kernel_launch(void* const* d_in, const int* in_sizes, int n_in,
                              void* d_out, int out_size, void* d_ws,
                              size_t ws_size, hipStream_t stream) {
  const float* x   = (const float*)d_in[0];  // [8,2048,1024]
  const float* ctx = (const float*)d_in[1];  // [8,2048,1024]
  const int*   msk = (const int*)d_in[2];    // [8,2048,2048]
  const float* Wq  = (const float*)d_in[3];  // [1024,1024] == B^T layout
  const float* bq  = (const float*)d_in[4];
  const float* Wk  = (const float*)d_in[5];
  const float* bk  = (const float*)d_in[6];
  const float* Wv  = (const float*)d_in[7];
  const float* bv  = (const float*)d_in[8];

  float* out = (float*)d_out;   // 8*2048*1024
  float* att = out + 16777216;  // 8*2048*2048

  // ws plan (128 MiB total, same footprint as R1):
  //   [0 .. 33.5MB)  xb   -> later Vt   (xb dead after Q projection)
  //   [33.5 .. 67)   cb
  //   [67 .. 100.5)  Q    -> later attb (spans Q+K, dead after QK^T)
  //   [100.5 .. 134) K
  u16* xb = (u16*)d_ws;
  u16* cb = xb + 16777216;
  u16* Q  = cb + 16777216;
  u16* Kb = Q + 16777216;
  u16* Vt = xb;
  u16* attb = Q;

  dim3 blk(256);
  const long long SQ = 2048LL * 1024, SS = 2048LL * 2048, SV = 1024LL * 2048;

  cast2<<<dim3(16384, 2), blk, 0, stream>>>(x, ctx, xb, cb);

  // projections: M=16384, N=1024, K=1024 (order matters: Q before V, V writes xb region)
  gemm_bt<true, u16, EPI_BIAS><<<dim3(8, 128, 1), blk, 0, stream>>>(
      xb, Wq, Q, bq, nullptr, 0.f, 16384, 1024, 1024, 0, 0, 0, 0);
  gemm_bt<true, u16, EPI_BIAS><<<dim3(8, 128, 1), blk, 0, stream>>>(
      cb, Wk, Kb, bk, nullptr, 0.f, 16384, 1024, 1024, 0, 0, 0, 0);
  gemm_bt<true, u16, EPI_BIAS_T><<<dim3(8, 128, 1), blk, 0, stream>>>(
      cb, Wv, Vt, bv, nullptr, 0.f, 16384, 1024, 1024, 0, 0, 0, 0);

  // logits = Q K^T * scale, masked -> att (fp32)
  gemm_bt<false, float, EPI_MASK><<<dim3(16, 16, 8), blk, 0, stream>>>(
      Q, Kb, att, nullptr, msk, 0.03125f, 2048, 2048, 1024, SQ, SQ, SS, SS);

  softmax_rows<<<dim3(16384), blk, 0, stream>>>(att, attb);

  // out = att @ V : A=attb bf16, Bt=Vt bf16
  gemm_bt<false, float, EPI_NONE><<<dim3(8, 16, 8), blk, 0, stream>>>(
      attb, Vt, out, nullptr, nullptr, 0.f, 2048, 1024, 2048, SS, SV, SQ, 0);
}

// Round 3
// 792.132 us; speedup vs baseline: 1.2781x; 1.1440x over previous
//
#include <hip/hip_runtime.h>
#include <hip/hip_bf16.h>
#include <type_traits>

typedef __attribute__((ext_vector_type(8))) __bf16 bf16x8;
typedef __attribute__((ext_vector_type(4))) float f32x4;
typedef unsigned short u16;

__device__ __forceinline__ u16 f2b(float x) {
  union { __hip_bfloat16 b; u16 u; } cv;
  cv.b = __float2bfloat16(x);
  return cv.u;
}

// async global->LDS, 16 B per lane. LDS dst = wave-uniform base + lane*16.
__device__ __forceinline__ void ld16(const u16* g, u16* l) {
  __builtin_amdgcn_global_load_lds(
      (const __attribute__((address_space(1))) unsigned int*)g,
      (__attribute__((address_space(3))) unsigned int*)l, 16, 0, 0);
}

// BK=64: row stride 128 B == 32 banks, so chunk c of row r is stored at slot
// c ^ (r&7) (8 chunks of 8 bf16 per row). Staging implements the swizzle by
// permuting each lane's GLOBAL source column (LDS dst of global_load_lds is
// pinned to base + lane*16). Frag reads land on 8 distinct 4-bank groups,
// 2 lanes each -> conflict-free (m136: 2-way is free).
constexpr int BM = 128, BN = 128, BK = 64;

enum { EPI_NONE = 0, EPI_BIAS = 1, EPI_BIAS_T = 2, EPI_MASK = 3 };

// C[m,n] = sum_k A[m,k] * Bt[n,k] (+ epilogue). A,Bt bf16, async-staged.
// EPI_BIAS_T: C = Vt [8][1024][2048] bf16, written transposed (seq=2048).
template <typename TC, int EPI>
__global__ __launch_bounds__(256) void gemm_bt(
    const u16* __restrict__ A, const u16* __restrict__ Bt, TC* __restrict__ C,
    const float* __restrict__ bias, const int* __restrict__ mask, float scale,
    int N, int K, long long sA, long long sB, long long sC, long long sM) {
  __shared__ u16 As[BM * BK];  // 16 KB
  __shared__ u16 Bs[BN * BK];  // 16 KB

  const int bz = blockIdx.z;
  A += (size_t)bz * sA;
  Bt += (size_t)bz * sB;
  C += (size_t)bz * sC;
  const long long maskBase = (long long)bz * sM;

  const int m0 = blockIdx.y * BM, n0 = blockIdx.x * BN;
  const int t = threadIdx.x, wave = t >> 6, lane = t & 63;
  const int wm = (wave >> 1) * 64, wn = (wave & 1) * 64;
  const int fr = lane & 15, quad = lane >> 4;

  // staging: lane covers row (lane>>3), swizzled chunk (lane&7)^(lane>>3)
  const int lr = lane >> 3, lc = lane & 7;
  const int cg = (lc ^ lr) * 8;  // global col chunk (elems)
  const u16* ga = A + (size_t)(m0 + wave * 32 + lr) * K + cg;
  const u16* gb = Bt + (size_t)(n0 + wave * 32 + lr) * K + cg;

  f32x4 acc[4][4] = {};

  for (int k0 = 0; k0 < K; k0 += BK) {
#pragma unroll
    for (int p = 0; p < 4; ++p) {
      ld16(ga + (size_t)(8 * p) * K, &As[(wave * 32 + 8 * p) * BK]);
      ld16(gb + (size_t)(8 * p) * K, &Bs[(wave * 32 + 8 * p) * BK]);
    }
    ga += BK;
    gb += BK;
    __builtin_amdgcn_s_waitcnt(0x0f70);  // vmcnt(0): async LDS writes landed
    __syncthreads();

#pragma unroll
    for (int ks = 0; ks < 2; ++ks) {
      bf16x8 af[4], bfr[4];
#pragma unroll
      for (int i = 0; i < 4; ++i)
        af[i] = *(const bf16x8*)
            &As[(wm + i * 16 + fr) * BK + (((ks * 4 + quad) ^ (fr & 7)) * 8)];
#pragma unroll
      for (int j = 0; j < 4; ++j)
        bfr[j] = *(const bf16x8*)
            &Bs[(wn + j * 16 + fr) * BK + (((ks * 4 + quad) ^ (fr & 7)) * 8)];
#pragma unroll
      for (int i = 0; i < 4; ++i)
#pragma unroll
        for (int j = 0; j < 4; ++j)
          acc[i][j] = __builtin_amdgcn_mfma_f32_16x16x32_bf16(
              af[i], bfr[j], acc[i][j], 0, 0, 0);
    }
    __syncthreads();
  }

  // C/D layout: col = lane&15 (fr), row = quad*4 + reg
#pragma unroll
  for (int i = 0; i < 4; ++i)
#pragma unroll
    for (int j = 0; j < 4; ++j) {
      const int mb = m0 + wm + i * 16 + quad * 4;
      const int n = n0 + wn + j * 16 + fr;
      if constexpr (EPI == EPI_BIAS_T) {
        const float bb = bias[n];
        const int b = mb >> 11, ml = mb & 2047;  // seq = 2048 per batch
        ushort4 o;
        o.x = f2b(acc[i][j][0] + bb);
        o.y = f2b(acc[i][j][1] + bb);
        o.z = f2b(acc[i][j][2] + bb);
        o.w = f2b(acc[i][j][3] + bb);
        *(ushort4*)&((u16*)C)[(size_t)b * 2097152 + (size_t)n * 2048 + ml] = o;
      } else {
#pragma unroll
        for (int r = 0; r < 4; ++r) {
          const int m = mb + r;
          float v = acc[i][j][r];
          if constexpr (EPI == EPI_BIAS) v += bias[n];
          if constexpr (EPI == EPI_MASK)
            v = mask[maskBase + (size_t)m * N + n] ? -1e9f : v * scale;
          if constexpr (std::is_same_v<TC, u16>)
            C[(size_t)m * N + n] = f2b(v);
          else
            C[(size_t)m * N + n] = v;
        }
      }
    }
}

// ---------------------------------------------------------------------------
// fp32 -> bf16 casts for x, ctx, Wq, Wk, Wv in one 1-D launch.
// blocks: [0,16384) x, [16384,32768) ctx, then 3x1024 for the weights.
// ---------------------------------------------------------------------------
__global__ __launch_bounds__(256) void cast_all(
    const float* __restrict__ x, const float* __restrict__ ctx,
    const float* __restrict__ wq, const float* __restrict__ wk,
    const float* __restrict__ wv, u16* __restrict__ xb, u16* __restrict__ cb,
    u16* __restrict__ wqb, u16* __restrict__ wkb, u16* __restrict__ wvb) {
  int b = blockIdx.x;
  const float* s;
  u16* d;
  size_t off;
  if (b < 16384) { s = x; d = xb; off = b; }
  else if (b < 32768) { s = ctx; d = cb; off = b - 32768 + 16384; }
  else if (b < 33792) { s = wq; d = wqb; off = b - 32768; }
  else if (b < 34816) { s = wk; d = wkb; off = b - 33792; }
  else { s = wv; d = wvb; off = b - 34816; }
  const size_t i = (off * 256 + threadIdx.x) * 4;
  float4 v = *(const float4*)&s[i];
  ushort4 h;
  h.x = f2b(v.x); h.y = f2b(v.y); h.z = f2b(v.z); h.w = f2b(v.w);
  *(ushort4*)&d[i] = h;
}

// ---------------------------------------------------------------------------
// In-place row softmax over att [16384][2048] fp32 + bf16 copy for AV GEMM.
// ---------------------------------------------------------------------------
__device__ __forceinline__ float blockReduceMax(float v, float* red) {
#pragma unroll
  for (int o = 32; o > 0; o >>= 1) v = fmaxf(v, __shfl_down(v, o));
  int t = threadIdx.x;
  if ((t & 63) == 0) red[t >> 6] = v;
  __syncthreads();
  float r = fmaxf(fmaxf(red[0], red[1]), fmaxf(red[2], red[3]));
  __syncthreads();
  return r;
}

__device__ __forceinline__ float blockReduceSum(float v, float* red) {
#pragma unroll
  for (int o = 32; o > 0; o >>= 1) v += __shfl_down(v, o);
  int t = threadIdx.x;
  if ((t & 63) == 0) red[t >> 6] = v;
  __syncthreads();
  float r = red[0] + red[1] + red[2] + red[3];
  __syncthreads();
  return r;
}

__global__ __launch_bounds__(256) void softmax_rows(float* __restrict__ att,
                                                    u16* __restrict__ attb) {
  __shared__ float red[4];
  float* p = att + (size_t)blockIdx.x * 2048;
  u16* pb = attb + (size_t)blockIdx.x * 2048;
  const int t = threadIdx.x;
  float4 v0 = ((const float4*)p)[t];
  float4 v1 = ((const float4*)p)[t + 256];
  float mx = fmaxf(fmaxf(fmaxf(v0.x, v0.y), fmaxf(v0.z, v0.w)),
                   fmaxf(fmaxf(v1.x, v1.y), fmaxf(v1.z, v1.w)));
  mx = blockReduceMax(mx, red);
  float4 e0, e1;
  e0.x = __expf(v0.x - mx); e0.y = __expf(v0.y - mx);
  e0.z = __expf(v0.z - mx); e0.w = __expf(v0.w - mx);
  e1.x = __expf(v1.x - mx); e1.y = __expf(v1.y - mx);
  e1.z = __expf(v1.z - mx); e1.w = __expf(v1.w - mx);
  float s = (e0.x + e0.y + e0.z + e0.w) + (e1.x + e1.y + e1.z + e1.w);
  s = blockReduceSum(s, red);
  float inv = 1.0f / s;
  e0.x *= inv; e0.y *= inv; e0.z *= inv; e0.w *= inv;
  e1.x *= inv; e1.y *= inv; e1.z *= inv; e1.w *= inv;
  ((float4*)p)[t] = e0;
  ((float4*)p)[t + 256] = e1;
  ushort4 h0, h1;
  h0.x = f2b(e0.x); h0.y = f2b(e0.y); h0.z = f2b(e0.z); h0.w = f2b(e0.w);
  h1.x = f2b(e1.x); h1.y = f2b(e1.y); h1.z = f2b(e1.z); h1.w = f2b(e1.w);
  *(ushort4*)&pb[(size_t)t * 4] = h0;
  *(ushort4*)&pb[(size_t)(t + 256) * 4] = h1;
}

// ---------------------------------------------------------------------------
extern "C" void kernel_launch(void* const* d_in, const int* in_sizes, int n_in,
                              void* d_out, int out_size, void* d_ws,
                              size_t ws_size, hipStream_t stream) {
  const float* x   = (const float*)d_in[0];  // [8,2048,1024]
  const float* ctx = (const float*)d_in[1];  // [8,2048,1024]
  const int*   msk = (const int*)d_in[2];    // [8,2048,2048]
  const float* Wq  = (const float*)d_in[3];  // [1024,1024] == B^T layout
  const float* bq  = (const float*)d_in[4];
  const float* Wk  = (const float*)d_in[5];
  const float* bk  = (const float*)d_in[6];
  const float* Wv  = (const float*)d_in[7];
  const float* bv  = (const float*)d_in[8];

  float* out = (float*)d_out;   // 8*2048*1024
  float* att = out + 16777216;  // 8*2048*2048

  // ws (134 MB): xb | cb | Q | Kb.  Aliases: Vt<-xb (dead after Q proj),
  // attb<-Q+Kb (dead after QK^T).
  u16* xb = (u16*)d_ws;
  u16* cb = xb + 16777216;
  u16* Q  = cb + 16777216;
  u16* Kb = Q + 16777216;
  u16* Vt = xb;
  u16* attb = Q;
  // bf16 weights live in the att region of d_out; dead before QK^T writes it.
  u16* wqb = (u16*)att;
  u16* wkb = wqb + 1048576;
  u16* wvb = wkb + 1048576;

  dim3 blk(256);
  const long long SQ = 2048LL * 1024, SS = 2048LL * 2048, SV = 1024LL * 2048;

  cast_all<<<dim3(35840), blk, 0, stream>>>(x, ctx, Wq, Wk, Wv, xb, cb, wqb,
                                            wkb, wvb);

  // projections: M=16384, N=1024, K=1024 (Q first: V overwrites xb region)
  gemm_bt<u16, EPI_BIAS><<<dim3(8, 128, 1), blk, 0, stream>>>(
      xb, wqb, Q, bq, nullptr, 0.f, 1024, 1024, 0, 0, 0, 0);
  gemm_bt<u16, EPI_BIAS><<<dim3(8, 128, 1), blk, 0, stream>>>(
      cb, wkb, Kb, bk, nullptr, 0.f, 1024, 1024, 0, 0, 0, 0);
  gemm_bt<u16, EPI_BIAS_T><<<dim3(8, 128, 1), blk, 0, stream>>>(
      cb, wvb, Vt, bv, nullptr, 0.f, 1024, 1024, 0, 0, 0, 0);

  // logits = Q K^T * scale, masked -> att (fp32, overwrites weight scratch)
  gemm_bt<float, EPI_MASK><<<dim3(16, 16, 8), blk, 0, stream>>>(
      Q, Kb, att, nullptr, msk, 0.03125f, 2048, 1024, SQ, SQ, SS, SS);

  softmax_rows<<<dim3(16384), blk, 0, stream>>>(att, attb);

  // out = att @ V : A=attb bf16, Bt=Vt bf16
  gemm_bt<float, EPI_NONE><<<dim3(8, 16, 8), blk, 0, stream>>>(
      attb, Vt, out, nullptr, nullptr, 0.f, 1024, 2048, SS, SV, SQ, 0);
}